// Round 1
// baseline (504.812 us; speedup 1.0000x reference)
//
#include <hip/hip_runtime.h>

// out = (1/(B*F)) * sum_{i,f} w[cls_i] * (x_if - t_if)^2  +  sum_i pen(t_{i,1})
// B=2e6, F=21, cls_i = t[i*21+2]/100 - 1, pen(v)= v<0 ? v^2 : (v>1000 ? (v-1000)^2 : 0)

#define TOTAL_ELEMS 42000000     // B*F
#define NVEC (TOTAL_ELEMS / 4)   // 10,500,000
#define NBLK 2048
#define NTHR 256

__global__ __launch_bounds__(NTHR) void wmse_main(
    const float* __restrict__ x, const int* __restrict__ t,
    const float* __restrict__ w, float* __restrict__ acc)
{
    __shared__ float ws[8];
    if (threadIdx.x < 7) ws[threadIdx.x] = w[threadIdx.x];
    __syncthreads();

    float amain = 0.f, apen = 0.f;
    const int stride = gridDim.x * blockDim.x;
    for (int v = blockIdx.x * blockDim.x + threadIdx.x; v < NVEC; v += stride) {
        const int idx0 = v << 2;
        float4 xf = reinterpret_cast<const float4*>(x)[v];
        int4  ti  = reinterpret_cast<const int4*>(t)[v];
        float xs[4] = {xf.x, xf.y, xf.z, xf.w};
        int   tv[4] = {ti.x, ti.y, ti.z, ti.w};

        // a 4-element vector spans at most 2 rows
        const int rowA = idx0 / 21;             // compiler emits magic-mul
        const int colA = idx0 - rowA * 21;
        const int rowB = (idx0 + 3) / 21;
        const float wA = ws[t[rowA * 21 + 2] / 100 - 1];   // L1-hot scalar load
        const float wB = ws[t[rowB * 21 + 2] / 100 - 1];

        #pragma unroll
        for (int j = 0; j < 4; ++j) {
            const int col  = colA + j;
            const float wj = (col < 21) ? wA : wB;
            const int  ccol = (col < 21) ? col : col - 21;
            const float tf = (float)tv[j];
            const float d  = xs[j] - tf;
            amain = fmaf(wj * d, d, amain);
            if (ccol == 1) {   // exactly once per row across the whole grid
                const float p = tf < 0.f ? tf * tf
                              : (tf > 1000.f ? (tf - 1000.f) * (tf - 1000.f) : 0.f);
                apen += p;
            }
        }
    }

    // wave64 butterfly reduce, then one atomic per wave
    #pragma unroll
    for (int off = 32; off > 0; off >>= 1) {
        amain += __shfl_down(amain, off);
        apen  += __shfl_down(apen,  off);
    }
    if ((threadIdx.x & 63) == 0) {
        atomicAdd(&acc[0], amain);
        atomicAdd(&acc[1], apen);
    }
}

__global__ void wmse_fin(const float* __restrict__ acc, float* __restrict__ out)
{
    out[0] = acc[0] * (1.0f / (2000000.0f * 21.0f)) + acc[1];
}

extern "C" void kernel_launch(void* const* d_in, const int* in_sizes, int n_in,
                              void* d_out, int out_size, void* d_ws, size_t ws_size,
                              hipStream_t stream)
{
    const float* x = (const float*)d_in[0];   // inputs  [B,F] f32
    const int*   t = (const int*)d_in[1];     // targets [B,F] i32
    const float* w = (const float*)d_in[2];   // weights [7]   f32
    float* acc = (float*)d_ws;                // ws re-poisoned every call -> zero it
    hipMemsetAsync(acc, 0, 2 * sizeof(float), stream);
    wmse_main<<<NBLK, NTHR, 0, stream>>>(x, t, w, acc);
    wmse_fin<<<1, 1, 0, stream>>>(acc, (float*)d_out);
}

// Round 2
// 339.422 us; speedup vs baseline: 1.4873x; 1.4873x over previous
//
#include <hip/hip_runtime.h>

// out = (1/(B*F)) * sum_{i,f} w[cls_i] * (x_if - t_if)^2  +  sum_i pen(t_{i,1})
// B=2e6, F=21, cls_i = t[i*21+2]/100 - 1, pen(v)= v<0 ? v^2 : (v>1000 ? (v-1000)^2 : 0)
// Two-stage reduction: NO global atomics (R1: 16384 same-line atomics -> 282us serialization).

#define TOTAL_ELEMS 42000000     // B*F
#define NVEC (TOTAL_ELEMS / 4)   // 10,500,000 float4/int4 chunks
#define NBLK 2048
#define NTHR 256

__device__ __forceinline__ void accum4(int v, const float* __restrict__ x,
                                       const int* __restrict__ t, const float* ws,
                                       float& amain, float& apen)
{
    const int idx0 = v << 2;
    const float4 xf = reinterpret_cast<const float4*>(x)[v];
    const int4   ti = reinterpret_cast<const int4*>(t)[v];
    // a 4-element chunk spans at most 2 rows of 21
    const int rowA = idx0 / 21;                     // magic-mul
    const int colA = idx0 - rowA * 21;
    const int rowB = (idx0 + 3) / 21;
    const float wA = ws[t[rowA * 21 + 2] / 100 - 1];  // L1-hot
    const float wB = ws[t[rowB * 21 + 2] / 100 - 1];
    const float xs[4] = {xf.x, xf.y, xf.z, xf.w};
    const int   tv[4] = {ti.x, ti.y, ti.z, ti.w};
    #pragma unroll
    for (int j = 0; j < 4; ++j) {
        const int col   = colA + j;
        const float wj  = (col < 21) ? wA : wB;
        const int  ccol = (col < 21) ? col : col - 21;
        const float tf  = (float)tv[j];
        const float d   = xs[j] - tf;
        amain = fmaf(wj * d, d, amain);
        if (ccol == 1) {   // exactly once per row across the whole grid
            apen += tf < 0.f ? tf * tf
                  : (tf > 1000.f ? (tf - 1000.f) * (tf - 1000.f) : 0.f);
        }
    }
}

__global__ __launch_bounds__(NTHR) void wmse_main(
    const float* __restrict__ x, const int* __restrict__ t,
    const float* __restrict__ w, float* __restrict__ part)
{
    __shared__ float ws[8];
    if (threadIdx.x < 7) ws[threadIdx.x] = w[threadIdx.x];
    __syncthreads();

    // 2 independent chunks per iteration: split accumulators, 4 loads in flight
    float am0 = 0.f, am1 = 0.f, ap0 = 0.f, ap1 = 0.f;
    const int stride = NBLK * NTHR;
    for (int v = blockIdx.x * NTHR + threadIdx.x; v < NVEC; v += 2 * stride) {
        accum4(v, x, t, ws, am0, ap0);
        if (v + stride < NVEC) accum4(v + stride, x, t, ws, am1, ap1);
    }
    float amain = am0 + am1, apen = ap0 + ap1;

    // wave64 butterfly, then cross-wave via LDS, one partial pair per block
    #pragma unroll
    for (int off = 32; off > 0; off >>= 1) {
        amain += __shfl_down(amain, off);
        apen  += __shfl_down(apen,  off);
    }
    __shared__ float rm[4], rp[4];
    const int wid = threadIdx.x >> 6;
    if ((threadIdx.x & 63) == 0) { rm[wid] = amain; rp[wid] = apen; }
    __syncthreads();
    if (threadIdx.x == 0) {
        part[2 * blockIdx.x]     = rm[0] + rm[1] + rm[2] + rm[3];
        part[2 * blockIdx.x + 1] = rp[0] + rp[1] + rp[2] + rp[3];
    }
}

__global__ __launch_bounds__(256) void wmse_reduce(
    const float* __restrict__ part, float* __restrict__ out)
{
    float m = 0.f, p = 0.f;
    for (int i = threadIdx.x; i < NBLK; i += 256) {
        m += part[2 * i];
        p += part[2 * i + 1];
    }
    #pragma unroll
    for (int off = 32; off > 0; off >>= 1) {
        m += __shfl_down(m, off);
        p += __shfl_down(p, off);
    }
    __shared__ float rm[4], rp[4];
    const int wid = threadIdx.x >> 6;
    if ((threadIdx.x & 63) == 0) { rm[wid] = m; rp[wid] = p; }
    __syncthreads();
    if (threadIdx.x == 0) {
        out[0] = (rm[0] + rm[1] + rm[2] + rm[3]) * (1.0f / 42000000.0f)
               + (rp[0] + rp[1] + rp[2] + rp[3]);
    }
}

extern "C" void kernel_launch(void* const* d_in, const int* in_sizes, int n_in,
                              void* d_out, int out_size, void* d_ws, size_t ws_size,
                              hipStream_t stream)
{
    const float* x = (const float*)d_in[0];   // inputs  [B,F] f32
    const int*   t = (const int*)d_in[1];     // targets [B,F] i32
    const float* w = (const float*)d_in[2];   // weights [7]   f32
    float* part = (float*)d_ws;               // 2048*2 floats = 16 KB, all written
    wmse_main<<<NBLK, NTHR, 0, stream>>>(x, t, w, part);
    wmse_reduce<<<1, 256, 0, stream>>>(part, (float*)d_out);
}

// Round 3
// 337.336 us; speedup vs baseline: 1.4965x; 1.0062x over previous
//
#include <hip/hip_runtime.h>

// out = (1/(B*F)) * sum_{i,f} w[cls_i] * (x_if - t_if)^2  +  sum_i pen(t_{i,1})
// B=2e6, F=21, cls_i = t[i*21+2]/100 - 1, pen(v) = (v - clamp(v,0,1000))^2
// R1: global atomics -> 282us serialization -> two-stage reduce (R2: 120us).
// R2: MLP=2 with guarded 2nd chunk -> latency-bound at 2.8 TB/s effective.
// R3: 4-deep unguarded unroll -> 8 independent 16B loads in flight per thread.

#define TOTAL_ELEMS 42000000     // B*F
#define NVEC (TOTAL_ELEMS / 4)   // 10,500,000 float4/int4 chunks
#define NBLK 2048
#define NTHR 256
#define GSTRIDE (NBLK * NTHR)    // 524,288

__device__ __forceinline__ void accum4(int v, const float* __restrict__ x,
                                       const int* __restrict__ t, const float* ws,
                                       float& amain, float& apen)
{
    const int idx0 = v << 2;
    const float4 xf = reinterpret_cast<const float4*>(x)[v];
    const int4   ti = reinterpret_cast<const int4*>(t)[v];
    // a 4-element chunk spans at most 2 rows of 21
    const int rowA = idx0 / 21;                        // magic-mul
    const int colA = idx0 - rowA * 21;
    const int rowB = (idx0 + 3) / 21;
    const float wA = ws[t[rowA * 21 + 2] / 100 - 1];   // L1-hot scalar load
    const float wB = ws[t[rowB * 21 + 2] / 100 - 1];
    const float xs[4] = {xf.x, xf.y, xf.z, xf.w};
    const int   tv[4] = {ti.x, ti.y, ti.z, ti.w};
    #pragma unroll
    for (int j = 0; j < 4; ++j) {
        const int col   = colA + j;
        const float wj  = (col < 21) ? wA : wB;
        const int  ccol = (col < 21) ? col : col - 21;
        const float tf  = (float)tv[j];
        const float d   = xs[j] - tf;
        amain = fmaf(wj * d, d, amain);
        if (ccol == 1) {   // exactly once per row across the whole grid
            const float r = tf - fminf(fmaxf(tf, 0.f), 1000.f);  // v_med3 residual
            apen = fmaf(r, r, apen);
        }
    }
}

__global__ __launch_bounds__(NTHR) void wmse_main(
    const float* __restrict__ x, const int* __restrict__ t,
    const float* __restrict__ w, float* __restrict__ part)
{
    __shared__ float ws[8];
    if (threadIdx.x < 7) ws[threadIdx.x] = w[threadIdx.x];
    __syncthreads();

    // 4 independent chunks per iteration, all loads unconditional -> 8 loads in flight
    float am[4] = {0.f, 0.f, 0.f, 0.f};
    float ap[4] = {0.f, 0.f, 0.f, 0.f};
    int v = blockIdx.x * NTHR + threadIdx.x;
    for (; v + 3 * GSTRIDE < NVEC; v += 4 * GSTRIDE) {
        #pragma unroll
        for (int u = 0; u < 4; ++u)
            accum4(v + u * GSTRIDE, x, t, ws, am[u], ap[u]);
    }
    for (; v < NVEC; v += GSTRIDE)    // remainder (<= 3 chunks per thread)
        accum4(v, x, t, ws, am[0], ap[0]);

    float amain = (am[0] + am[1]) + (am[2] + am[3]);
    float apen  = (ap[0] + ap[1]) + (ap[2] + ap[3]);

    // wave64 butterfly, then cross-wave via LDS, one partial pair per block
    #pragma unroll
    for (int off = 32; off > 0; off >>= 1) {
        amain += __shfl_down(amain, off);
        apen  += __shfl_down(apen,  off);
    }
    __shared__ float rm[4], rp[4];
    const int wid = threadIdx.x >> 6;
    if ((threadIdx.x & 63) == 0) { rm[wid] = amain; rp[wid] = apen; }
    __syncthreads();
    if (threadIdx.x == 0) {
        part[2 * blockIdx.x]     = rm[0] + rm[1] + rm[2] + rm[3];
        part[2 * blockIdx.x + 1] = rp[0] + rp[1] + rp[2] + rp[3];
    }
}

__global__ __launch_bounds__(256) void wmse_reduce(
    const float* __restrict__ part, float* __restrict__ out)
{
    float m = 0.f, p = 0.f;
    for (int i = threadIdx.x; i < NBLK; i += 256) {
        m += part[2 * i];
        p += part[2 * i + 1];
    }
    #pragma unroll
    for (int off = 32; off > 0; off >>= 1) {
        m += __shfl_down(m, off);
        p += __shfl_down(p, off);
    }
    __shared__ float rm[4], rp[4];
    const int wid = threadIdx.x >> 6;
    if ((threadIdx.x & 63) == 0) { rm[wid] = m; rp[wid] = p; }
    __syncthreads();
    if (threadIdx.x == 0) {
        out[0] = (rm[0] + rm[1] + rm[2] + rm[3]) * (1.0f / 42000000.0f)
               + (rp[0] + rp[1] + rp[2] + rp[3]);
    }
}

extern "C" void kernel_launch(void* const* d_in, const int* in_sizes, int n_in,
                              void* d_out, int out_size, void* d_ws, size_t ws_size,
                              hipStream_t stream)
{
    const float* x = (const float*)d_in[0];   // inputs  [B,F] f32
    const int*   t = (const int*)d_in[1];     // targets [B,F] i32
    const float* w = (const float*)d_in[2];   // weights [7]   f32
    float* part = (float*)d_ws;               // 2048*2 floats = 16 KB, all written
    wmse_main<<<NBLK, NTHR, 0, stream>>>(x, t, w, part);
    wmse_reduce<<<1, 256, 0, stream>>>(part, (float*)d_out);
}